// Round 15
// baseline (59.217 us; speedup 1.0000x reference)
//
#include <hip/hip_runtime.h>
#include <stdint.h>
#include <stddef.h>

// MMD loss, fused: gram = X·X^T (bf16 MFMA) + 5-kernel RBF epilogue + signed mean.
// N=8192 rows (4096 src + 4096 tgt), D=256.
//
// Round-15: OCCUPANCY-FIRST retiling. R14 evidence: cross-tile prefetch = 0,
// steady state bound by TLP (2 waves/SIMD: 4-wave blocks + 64KB LDS -> 2
// blocks/CU). NEW: 64x256 tiles, 8 waves/block (512thr), wave = 64x32 strip
// (acc 32 regs), A panel 32KB LDS, B 4-deep ring (16 regs); live ~116 <= 128
// -> __launch_bounds__(512,4), 16 waves/CU = 4/SIMD (2x TLP), no spill.
// Upper-tri via 2112 tiles (row-block i in 0..127, col-block j >= i>>2),
// per-element weight {0 below diag, 1 diag, 2 above} in epilogue; sign
// uniform per tile (64 | 4096, 256 | 4096). Kept: zero device-scope
// serialization, plain-store partials, fragment-transposed Xbt, XCD swizzle,
// forced B-ring pipeline (R13's proven win).
//
// Fragment layout: elem(r,k) at (r>>4)*4096 + (k>>3)*128 + (r&15)*8 + (k&7)
// -> lane(lo,hi) fragment base byte = rowgroup*8192 + (kc*4+hi)*256 + lo*16
//    (contiguous 1KB per wave per fragment; 64-row A panel = 32KB contig).
//
// ws layout:
//   [0]      float  coef            (-log2(e)/(16*bandwidth))
//   [64]     double partial[2112]   -> [64, 16960)
//   [20480]  float  csp[256*256]    -> [20480, 282624)
//   [282624] float  sq[8192]        -> [282624, 315392)
//   [315392] ushort Xbt[8192*256]   (bf16, fragment-transposed, 4MB)

#define N_TOT 8192
#define D_DIM 256
#define BS    4096
#define NTILE 2112    // 64x256 tiles covering upper triangle (8 | 2112)

typedef float  f32x4  __attribute__((ext_vector_type(4)));
typedef short  bf16x8 __attribute__((ext_vector_type(8)));

typedef __attribute__((address_space(1))) const unsigned int gas_u32;
typedef __attribute__((address_space(3))) unsigned int       lds_u32;

__device__ __forceinline__ unsigned short f2bf(float f) {
  unsigned u = __float_as_uint(f);
  u += 0x7fffu + ((u >> 16) & 1u);   // RNE; inputs are finite
  return (unsigned short)(u >> 16);
}
__device__ __forceinline__ float bf2f(unsigned short s) {
  return __uint_as_float(((unsigned)s) << 16);
}

// ---- prep: f32 -> bf16 fragment-transposed copy + row sq-norms + column partials ----
__global__ void prep_kernel(const float* __restrict__ src, const float* __restrict__ tgt,
                            unsigned short* __restrict__ Xbt, float* __restrict__ sq,
                            float* __restrict__ csp) {
  int tid  = threadIdx.x;
  int w    = tid >> 6, lane = tid & 63;
  int blk  = blockIdx.x;
  float4 cacc = {0.f, 0.f, 0.f, 0.f};

  #pragma unroll
  for (int r = 0; r < 4; ++r) {
    int row = blk * 32 + w * 4 + r;
    const float* rowp = (row < BS) ? (src + (size_t)row * D_DIM)
                                   : (tgt + (size_t)(row - BS) * D_DIM);
    float4 v = reinterpret_cast<const float4*>(rowp)[lane];   // cols k..k+3, k=lane*4
    cacc.x += v.x; cacc.y += v.y; cacc.z += v.z; cacc.w += v.w;
    ushort4 b;
    b.x = f2bf(v.x); b.y = f2bf(v.y); b.z = f2bf(v.z); b.w = f2bf(v.w);
    int k = lane * 4;
    size_t off = ((size_t)(row >> 4)) * 4096 + (size_t)(k >> 3) * 128
               + (size_t)((row & 15) * 8) + (k & 7);
    *reinterpret_cast<ushort4*>(Xbt + off) = b;
    float fx = bf2f(b.x), fy = bf2f(b.y), fz = bf2f(b.z), fw = bf2f(b.w);
    float s = fx * fx + fy * fy + fz * fz + fw * fw;
    #pragma unroll
    for (int o = 32; o; o >>= 1) s += __shfl_down(s, o, 64);
    if (lane == 0) sq[row] = s;
  }

  __shared__ float cs[8][256];
  reinterpret_cast<float4*>(&cs[w][0])[lane] = cacc;
  __syncthreads();
  if (tid < 256) {
    float s = 0.f;
    #pragma unroll
    for (int ww = 0; ww < 8; ++ww) s += cs[ww][tid];
    csp[blk * 256 + tid] = s;   // plain store, distinct address
  }
}

// ---- bandwidth coefficient (1 block; stream order = visibility) ----
__global__ void bw_kernel(const float* __restrict__ sq, const float* __restrict__ csp,
                          float* __restrict__ coef) {
  int t = threadIdx.x, w = t >> 6, lane = t & 63;
  double s1 = 0.0;
  #pragma unroll
  for (int i = 0; i < 32; ++i) s1 += (double)sq[t + i * 256];
  double c = 0.0;
  #pragma unroll 16
  for (int b = 0; b < 256; ++b) c += (double)csp[b * 256 + t];   // coalesced
  double s2 = c * c;
  #pragma unroll
  for (int o = 32; o; o >>= 1) { s1 += __shfl_down(s1, o, 64); s2 += __shfl_down(s2, o, 64); }
  __shared__ double rs[4], rs2[4];
  if (lane == 0) { rs[w] = s1; rs2[w] = s2; }
  __syncthreads();
  if (t == 0) {
    double S1 = rs[0] + rs[1] + rs[2] + rs[3];
    double S2 = rs2[0] + rs2[1] + rs2[2] + rs2[3];
    double S  = 2.0 * (double)N_TOT * S1 - 2.0 * S2;   // sum of all pairwise sq dists
    double bw = (S / ((double)N_TOT * (double)N_TOT - (double)N_TOT)) / 4.0;
    *coef = (float)(-1.4426950408889634 / (16.0 * bw));
  }
}

// ---- fused gram + RBF epilogue: 2112 blocks x 8 waves, 64x256 tiles ----
__launch_bounds__(512, 4)
__global__ void gram_kernel(const unsigned short* __restrict__ Xbt, const float* __restrict__ sq,
                            const float* __restrict__ coefp, double* __restrict__ partial) {
  __shared__ __align__(16) unsigned char Alds[32768];   // 64-row A panel

  int tid = threadIdx.x;
  int w = tid >> 6, lane = tid & 63;          // 8 waves; wave w = cols w*32..w*32+31
  const int lo = lane & 15, hi = lane >> 4;
  const int fragoff = hi * 256 + lo * 16;

  // XCD-contiguous swizzle (2112 = 8 * 264)
  int orig = (int)blockIdx.x;
  int blk  = (orig & 7) * (NTILE / 8) + (orig >> 3);

  // decode tile -> (i: 64-row block 0..127, j: 256-col block, j >= i>>2)
  // quad q (4 rows) has 4*(32-q) tiles, rows i=4q..4q+3, each with (32-q) tiles j=q..31
  int i, j;
  {
    int rem = blk, q = 0;
    while (rem >= 4 * (32 - q)) { rem -= 4 * (32 - q); ++q; }
    int per = 32 - q;
    i = q * 4 + rem / per;
    j = q + rem % per;
  }

  float sgn = ((i < 64) == (j < 16)) ? 1.f : -1.f;   // rows<4096 vs cols<4096

  const char* Xb = (const char*)Xbt;

  // B bases: wave w covers cols j*256 + w*32 .. +31 = rowgroups j*16 + 2w + {0,1}
  const char* pB0 = Xb + (size_t)(j * 16 + 2 * w) * 8192 + fragoff;
  const char* pB1 = pB0 + 8192;

  // preload B ring (4 kc deep, 8 outstanding 1KB loads) BEFORE A staging
  bf16x8 b[4][2], a[2][4];
  #pragma unroll
  for (int s = 0; s < 4; ++s) {
    b[s][0] = *(const bf16x8*)(pB0 + s * 1024);
    b[s][1] = *(const bf16x8*)(pB1 + s * 1024);
  }

  // stage A panel: rows i*64..+63 = bytes [i*32768, +32768), contiguous.
  // 8 waves x 4KB: 4 x global_load_lds width-16 each.
  {
    const char* srcA = Xb + (size_t)i * 32768 + w * 4096 + lane * 16;
    unsigned char* dstA = Alds + w * 4096;
    #pragma unroll
    for (int q2 = 0; q2 < 4; ++q2)
      __builtin_amdgcn_global_load_lds((gas_u32*)(srcA + q2 * 1024),
                                       (lds_u32*)(dstA + q2 * 1024), 16, 0, 0);
  }
  __syncthreads();   // drains staging (and the B preloads, already in flight)

  const char* pAl = (const char*)Alds + fragoff;

  f32x4 acc[4][2];
  #pragma unroll
  for (int m = 0; m < 4; ++m) {
    acc[m][0] = (f32x4){0.f, 0.f, 0.f, 0.f};
    acc[m][1] = (f32x4){0.f, 0.f, 0.f, 0.f};
  }

  #pragma unroll
  for (int m = 0; m < 4; ++m) a[0][m] = *(const bf16x8*)(pAl + m * 8192);

  #pragma unroll
  for (int kc = 0; kc < 8; ++kc) {
    if (kc + 1 < 8) {                        // A prefetch: disjoint ring slots
      #pragma unroll
      for (int m = 0; m < 4; ++m)
        a[(kc + 1) & 1][m] = *(const bf16x8*)(pAl + m * 8192 + (kc + 1) * 1024);
    }
    #pragma unroll
    for (int m = 0; m < 4; ++m) {
      acc[m][0] = __builtin_amdgcn_mfma_f32_16x16x32_bf16(a[kc & 1][m], b[kc & 3][0],
                                                          acc[m][0], 0, 0, 0);
      acc[m][1] = __builtin_amdgcn_mfma_f32_16x16x32_bf16(a[kc & 1][m], b[kc & 3][1],
                                                          acc[m][1], 0, 0, 0);
    }
    if (kc + 4 < 8) {                        // B prefetch AFTER last read of slot
      b[kc & 3][0] = *(const bf16x8*)(pB0 + (kc + 4) * 1024);
      b[kc & 3][1] = *(const bf16x8*)(pB1 + (kc + 4) * 1024);
    }
  }

  // epilogue: d2 = max(sq_i+sq_j-2g, 0); kernels = u+u^2+u^4+u^8+u^16, u=exp2(d2*coef)
  // weight: 0 below diagonal, 1 on it, 2 above (upper-tri + symmetry)
  float coef = *coefp;
  int rowbase = i * 64;
  int colbase = j * 256 + w * 32;
  float sqj[2], sqi[4][4];
  #pragma unroll
  for (int n = 0; n < 2; ++n) sqj[n] = sq[colbase + n * 16 + lo];
  #pragma unroll
  for (int m = 0; m < 4; ++m)
    #pragma unroll
    for (int r = 0; r < 4; ++r) sqi[m][r] = sq[rowbase + m * 16 + hi * 4 + r];

  float psum = 0.f;
  #pragma unroll
  for (int m = 0; m < 4; ++m) {
    #pragma unroll
    for (int n = 0; n < 2; ++n) {
      int col = colbase + n * 16 + lo;
      #pragma unroll
      for (int r = 0; r < 4; ++r) {
        int row = rowbase + m * 16 + hi * 4 + r;
        float wgt = (col > row) ? 2.f : ((col == row) ? 1.f : 0.f);
        float g  = acc[m][n][r];
        float d2 = fmaxf(fmaf(-2.f, g, sqi[m][r] + sqj[n]), 0.f);
        float u  = __builtin_amdgcn_exp2f(d2 * coef);
        float u2 = u * u, u4 = u2 * u2, u8 = u4 * u4, u16 = u8 * u8;
        psum += wgt * ((u + u2) + (u4 + u8) + u16);
      }
    }
  }
  #pragma unroll
  for (int o = 32; o; o >>= 1) psum += __shfl_down(psum, o, 64);

  __shared__ float wred[8];
  if (lane == 0) wred[w] = psum;
  __syncthreads();
  if (tid == 0) {
    float s = 0.f;
    #pragma unroll
    for (int ww = 0; ww < 8; ++ww) s += wred[ww];
    partial[blk] = (double)(s * sgn);   // plain store, distinct address
  }
}

// ---- final reduction (1 block; stream order = visibility) ----
__global__ void reduce_kernel(const double* __restrict__ partial, float* __restrict__ out) {
  int t = threadIdx.x, w = t >> 6, lane = t & 63;
  double s = 0.0;
  for (int i = t; i < NTILE; i += 256) s += partial[i];
  #pragma unroll
  for (int o = 32; o; o >>= 1) s += __shfl_down(s, o, 64);
  __shared__ double rs[4];
  if (lane == 0) rs[w] = s;
  __syncthreads();
  if (t == 0)
    out[0] = (float)((rs[0] + rs[1] + rs[2] + rs[3]) / ((double)BS * (double)BS));
}

extern "C" void kernel_launch(void* const* d_in, const int* in_sizes, int n_in,
                              void* d_out, int out_size, void* d_ws, size_t ws_size,
                              hipStream_t stream) {
  const float* src = (const float*)d_in[0];
  const float* tgt = (const float*)d_in[1];
  char* ws = (char*)d_ws;
  float*  coef    = (float*)(ws + 0);
  double* partial = (double*)(ws + 64);
  float*  csp     = (float*)(ws + 20480);
  float*  sq      = (float*)(ws + 282624);
  unsigned short* Xbt = (unsigned short*)(ws + 315392);
  float* out = (float*)d_out;

  prep_kernel<<<256, 512, 0, stream>>>(src, tgt, Xbt, sq, csp);
  bw_kernel<<<1, 256, 0, stream>>>(sq, csp, coef);
  gram_kernel<<<NTILE, 512, 0, stream>>>(Xbt, sq, coef, partial);
  reduce_kernel<<<1, 256, 0, stream>>>(partial, out);
}